// Round 3
// baseline (738.045 us; speedup 1.0000x reference)
//
#include <hip/hip_runtime.h>

#define NN 30000
#define NE 300000
#define D_IN 256
#define D_H 128
#define D_OUT 64
#define NL 6
#define D_JK (D_H * (NL + 1))   // 896

// ---------------------------------------------------------------------------
// int degree count per endpoint
// ---------------------------------------------------------------------------
__global__ void degree_kernel(const int* __restrict__ src, const int* __restrict__ dst,
                              int* __restrict__ outdeg, int* __restrict__ indeg) {
    int e = blockIdx.x * blockDim.x + threadIdx.x;
    if (e < NE) {
        atomicAdd(&outdeg[src[e]], 1);
        atomicAdd(&indeg[dst[e]], 1);
    }
}

__global__ void rsqrt_kernel(const int* __restrict__ deg, float* __restrict__ inv, int n) {
    int i = blockIdx.x * blockDim.x + threadIdx.x;
    if (i < n) {
        float d = (float)deg[i];
        inv[i] = rsqrtf(d < 1.0f ? 1.0f : d);
    }
}

// ---------------------------------------------------------------------------
// exclusive prefix scan of indeg[NN] -> row_ptr[NN+1], single block 1024 thr,
// wave-shuffle based (6 shfl per wave + 16-entry cross-wave scan)
// ---------------------------------------------------------------------------
__global__ __launch_bounds__(1024) void scan_kernel(const int* __restrict__ deg,
                                                    int* __restrict__ row_ptr) {
    __shared__ int wsum[16];
    __shared__ int chunk_base;
    if (threadIdx.x == 0) chunk_base = 0;
    __syncthreads();
    const int lane = threadIdx.x & 63;
    const int wid = threadIdx.x >> 6;
    for (int base = 0; base < NN; base += 1024) {
        int i = base + threadIdx.x;
        int v = (i < NN) ? deg[i] : 0;
        int s = v;
#pragma unroll
        for (int off = 1; off < 64; off <<= 1) {
            int t = __shfl_up(s, off, 64);
            if (lane >= off) s += t;
        }
        if (lane == 63) wsum[wid] = s;
        __syncthreads();
        if (wid == 0 && lane < 16) {
            int ws = wsum[lane];
#pragma unroll
            for (int off = 1; off < 16; off <<= 1) {
                int t = __shfl_up(ws, off, 64);
                if (lane >= off) ws += t;
            }
            wsum[lane] = ws;
        }
        __syncthreads();
        int cb = chunk_base;
        int woff = (wid > 0) ? wsum[wid - 1] : 0;
        if (i < NN) row_ptr[i] = cb + woff + s - v;
        int total = wsum[15];
        __syncthreads();
        if (threadIdx.x == 0) chunk_base = cb + total;
        __syncthreads();
    }
    if (threadIdx.x == 0) row_ptr[NN] = chunk_base;
}

// scatter edge sources into CSR col array (grouped by dst)
__global__ void fill_kernel(const int* __restrict__ src, const int* __restrict__ dst,
                            const int* __restrict__ row_ptr, int* __restrict__ cursor,
                            int* __restrict__ col) {
    int e = blockIdx.x * blockDim.x + threadIdx.x;
    if (e < NE) {
        int d = dst[e];
        int pos = atomicAdd(&cursor[d], 1);
        col[row_ptr[d] + pos] = src[e];
    }
}

// ---------------------------------------------------------------------------
// fp32 GEMM v2: Y[n, 0:M] = (X[n, 0:K] @ W[K, M]) * rowscale[n]
// 64-row x M-col tile, 8x8 microtile, transposed-X LDS, all-b128 LDS traffic.
//   M=128: 128 thr (16 cg x 8 rg), cols = {cg*4..+3} u {64+cg*4..+3}
//   M=64 :  64 thr ( 8 cg x 8 rg), cols = {cg*4..+3} u {32+cg*4..+3}
// ---------------------------------------------------------------------------
template <int M>
__global__ __launch_bounds__(M == 128 ? 128 : 64) void gemm_kernel(
    const float* __restrict__ X, int ldx, int K,
    const float* __restrict__ W,          // [K, M] row-major
    const float* __restrict__ rowscale,   // nullptr => 1.0
    float* __restrict__ Y, int ldy, int nrows)
{
    constexpr int BT = (M == 128) ? 128 : 64;   // threads
    constexpr int TR = 64;                      // rows per block
    constexpr int KB = 64;                      // K chunk
    constexpr int TRP = TR + 4;                 // 68: keeps 16B align, 2-way reads
    constexpr int CGN = M / 8;                  // col groups (8 cols each, split)
    constexpr int XF4 = TR * KB / 4 / BT;       // float4 X loads per thread
    constexpr int WF4 = KB * M / 4 / BT;        // float4 W loads per thread (16)

    __shared__ float Wl[KB * M];
    __shared__ float Xt[KB * TRP];              // transposed: Xt[k][row]

    const int tid = threadIdx.x;
    const int cg = tid % CGN;
    const int rg = tid / CGN;                   // 0..7
    const int row0 = blockIdx.x * TR;

    float acc[8][8];
#pragma unroll
    for (int r = 0; r < 8; r++)
#pragma unroll
        for (int c = 0; c < 8; c++) acc[r][c] = 0.f;

    for (int kb = 0; kb < K; kb += KB) {
        // --- stage W chunk [KB x M], row-major flat copy ---
        {
            const float* wsrc = W + (size_t)kb * M;
#pragma unroll
            for (int i = 0; i < WF4; i++) {
                int idx = (i * BT + tid) * 4;
                *(float4*)(Wl + idx) = *(const float4*)(wsrc + idx);
            }
        }
        // --- stage X tile transposed: Xt[k][r] ---
        {
#pragma unroll
            for (int i = 0; i < XF4; i++) {
                int flat = i * BT + tid;
                int r = flat / (KB / 4);
                int c4 = flat % (KB / 4);
                int grow = row0 + r;
                float4 v = make_float4(0.f, 0.f, 0.f, 0.f);
                if (grow < nrows)
                    v = *(const float4*)(X + (size_t)grow * ldx + kb + c4 * 4);
                Xt[(c4 * 4 + 0) * TRP + r] = v.x;
                Xt[(c4 * 4 + 1) * TRP + r] = v.y;
                Xt[(c4 * 4 + 2) * TRP + r] = v.z;
                Xt[(c4 * 4 + 3) * TRP + r] = v.w;
            }
        }
        __syncthreads();

#pragma unroll 4
        for (int k = 0; k < KB; k++) {
            float4 xa = *(const float4*)(Xt + k * TRP + rg * 8);
            float4 xb = *(const float4*)(Xt + k * TRP + rg * 8 + 4);
            float4 wa = *(const float4*)(Wl + k * M + cg * 4);
            float4 wb = *(const float4*)(Wl + k * M + cg * 4 + M / 2);
            float xr[8] = {xa.x, xa.y, xa.z, xa.w, xb.x, xb.y, xb.z, xb.w};
            float wc[8] = {wa.x, wa.y, wa.z, wa.w, wb.x, wb.y, wb.z, wb.w};
#pragma unroll
            for (int r = 0; r < 8; r++)
#pragma unroll
                for (int c = 0; c < 8; c++)
                    acc[r][c] = fmaf(xr[r], wc[c], acc[r][c]);
        }
        __syncthreads();
    }

    // --- epilogue ---
#pragma unroll
    for (int r = 0; r < 8; r++) {
        int grow = row0 + rg * 8 + r;
        if (grow < nrows) {
            float s = rowscale ? rowscale[grow] : 1.0f;
            float4 va = make_float4(acc[r][0] * s, acc[r][1] * s, acc[r][2] * s, acc[r][3] * s);
            float4 vb = make_float4(acc[r][4] * s, acc[r][5] * s, acc[r][6] * s, acc[r][7] * s);
            *(float4*)(Y + (size_t)grow * ldy + cg * 4) = va;
            *(float4*)(Y + (size_t)grow * ldy + cg * 4 + M / 2) = vb;
        }
    }
}

// ---------------------------------------------------------------------------
// CSR gather-reduce + epilogue:
//   Y[node, :] = act( (sum_{j in in(node)} T[col[j], :]) * scale[node] + bias )
// ---------------------------------------------------------------------------
template <int D, bool RELU>
__global__ void gather_kernel(const float* __restrict__ T,
                              const int* __restrict__ row_ptr,
                              const int* __restrict__ col,
                              const float* __restrict__ scale,  // nullptr => 1
                              const float* __restrict__ bias,   // [D]
                              float* __restrict__ Y, int ldy) {
    constexpr int Q = D / 4;
    int idx = blockIdx.x * blockDim.x + threadIdx.x;
    int node = idx / Q;
    int q = idx % Q;
    if (node >= NN) return;
    int beg = row_ptr[node];
    int end = row_ptr[node + 1];
    float4 acc = make_float4(0.f, 0.f, 0.f, 0.f);
    int j = beg;
    for (; j + 1 < end; j += 2) {
        int c0 = col[j], c1 = col[j + 1];
        float4 v0 = *(const float4*)(T + (size_t)c0 * D + q * 4);
        float4 v1 = *(const float4*)(T + (size_t)c1 * D + q * 4);
        acc.x += v0.x + v1.x;
        acc.y += v0.y + v1.y;
        acc.z += v0.z + v1.z;
        acc.w += v0.w + v1.w;
    }
    if (j < end) {
        int c0 = col[j];
        float4 v0 = *(const float4*)(T + (size_t)c0 * D + q * 4);
        acc.x += v0.x; acc.y += v0.y; acc.z += v0.z; acc.w += v0.w;
    }
    float s = scale ? scale[node] : 1.0f;
    float4 b = *(const float4*)(bias + q * 4);
    float4 h;
    h.x = fmaf(acc.x, s, b.x);
    h.y = fmaf(acc.y, s, b.y);
    h.z = fmaf(acc.z, s, b.z);
    h.w = fmaf(acc.w, s, b.w);
    if (RELU) {
        h.x = fmaxf(h.x, 0.f); h.y = fmaxf(h.y, 0.f);
        h.z = fmaxf(h.z, 0.f); h.w = fmaxf(h.w, 0.f);
    }
    *(float4*)(Y + (size_t)node * ldy + q * 4) = h;
}

// ---------------------------------------------------------------------------
extern "C" void kernel_launch(void* const* d_in, const int* in_sizes, int n_in,
                              void* d_out, int out_size, void* d_ws, size_t ws_size,
                              hipStream_t stream) {
    const float* feats = (const float*)d_in[0];
    const int*   src   = (const int*)d_in[1];
    const int*   dst   = (const int*)d_in[2];
    const float* W0    = (const float*)d_in[3];
    const float* b0    = (const float*)d_in[4];
    const float* Wh    = (const float*)d_in[5];   // [6,128,128]
    const float* bh    = (const float*)d_in[6];   // [6,128]
    const float* Wout  = (const float*)d_in[7];   // [896,64]
    const float* bout  = (const float*)d_in[8];
    float* out = (float*)d_out;

    float* ws      = (float*)d_ws;
    float* inv_out = ws;                          // NN
    float* inv_in  = ws + NN;                     // NN
    float* t       = ws + 2 * NN;                 // NN*128
    float* jk      = t + (size_t)NN * D_H;        // NN*896
    int* ibase     = (int*)(jk + (size_t)NN * D_JK);
    int* outdeg_i  = ibase;                       // NN
    int* indeg_i   = ibase + NN;                  // NN
    int* row_ptr   = ibase + 2 * NN;              // NN+1
    int* cursor    = ibase + 3 * NN + 1;          // NN
    int* col       = ibase + 4 * NN + 1;          // NE

    const int B = 256;
    const int gemm_blocks = (NN + 63) / 64;       // 469

    // ---- CSR build + norms ----
    hipMemsetAsync(outdeg_i, 0, 2 * NN * sizeof(int), stream);
    hipMemsetAsync(cursor, 0, NN * sizeof(int), stream);
    degree_kernel<<<(NE + B - 1) / B, B, 0, stream>>>(src, dst, outdeg_i, indeg_i);
    rsqrt_kernel<<<(2 * NN + B - 1) / B, B, 0, stream>>>(outdeg_i, inv_out, 2 * NN);
    scan_kernel<<<1, 1024, 0, stream>>>(indeg_i, row_ptr);
    fill_kernel<<<(NE + B - 1) / B, B, 0, stream>>>(src, dst, row_ptr, cursor, col);

    // ---- layer 0 ----
    gemm_kernel<128><<<gemm_blocks, 128, 0, stream>>>(feats, D_IN, D_IN, W0, inv_out, t, D_H, NN);
    gather_kernel<128, true><<<(NN * 32 + B - 1) / B, B, 0, stream>>>(
        t, row_ptr, col, inv_in, b0, jk, D_JK);

    // ---- layers 1..6 ----
    for (int l = 0; l < NL; l++) {
        gemm_kernel<128><<<gemm_blocks, 128, 0, stream>>>(
            jk + (size_t)l * D_H, D_JK, D_H, Wh + (size_t)l * D_H * D_H, inv_out, t, D_H, NN);
        gather_kernel<128, true><<<(NN * 32 + B - 1) / B, B, 0, stream>>>(
            t, row_ptr, col, inv_in, bh + (size_t)l * D_H, jk + (size_t)(l + 1) * D_H, D_JK);
    }

    // ---- final ----
    gemm_kernel<64><<<gemm_blocks, 64, 0, stream>>>(jk, D_JK, D_JK, Wout, nullptr, t, D_OUT, NN);
    gather_kernel<64, false><<<(NN * 16 + B - 1) / B, B, 0, stream>>>(
        t, row_ptr, col, nullptr, bout, out, D_OUT);
}

// Round 4
// 539.816 us; speedup vs baseline: 1.3672x; 1.3672x over previous
//
#include <hip/hip_runtime.h>

#define NN 30000
#define NE 300000
#define D_IN 256
#define D_H 128
#define D_OUT 64
#define NL 6

// ---------------------------------------------------------------------------
// int degree count per endpoint
// ---------------------------------------------------------------------------
__global__ void degree_kernel(const int* __restrict__ src, const int* __restrict__ dst,
                              int* __restrict__ outdeg, int* __restrict__ indeg) {
    int e = blockIdx.x * blockDim.x + threadIdx.x;
    if (e < NE) {
        atomicAdd(&outdeg[src[e]], 1);
        atomicAdd(&indeg[dst[e]], 1);
    }
}

__global__ void rsqrt_kernel(const int* __restrict__ deg, float* __restrict__ inv, int n) {
    int i = blockIdx.x * blockDim.x + threadIdx.x;
    if (i < n) {
        float d = (float)deg[i];
        inv[i] = rsqrtf(d < 1.0f ? 1.0f : d);
    }
}

// ---------------------------------------------------------------------------
// exclusive prefix scan of indeg[NN] -> row_ptr[NN+1], single block 1024 thr
// ---------------------------------------------------------------------------
__global__ __launch_bounds__(1024) void scan_kernel(const int* __restrict__ deg,
                                                    int* __restrict__ row_ptr) {
    __shared__ int wsum[16];
    __shared__ int chunk_base;
    if (threadIdx.x == 0) chunk_base = 0;
    __syncthreads();
    const int lane = threadIdx.x & 63;
    const int wid = threadIdx.x >> 6;
    for (int base = 0; base < NN; base += 1024) {
        int i = base + threadIdx.x;
        int v = (i < NN) ? deg[i] : 0;
        int s = v;
#pragma unroll
        for (int off = 1; off < 64; off <<= 1) {
            int t = __shfl_up(s, off, 64);
            if (lane >= off) s += t;
        }
        if (lane == 63) wsum[wid] = s;
        __syncthreads();
        if (wid == 0 && lane < 16) {
            int ws = wsum[lane];
#pragma unroll
            for (int off = 1; off < 16; off <<= 1) {
                int t = __shfl_up(ws, off, 64);
                if (lane >= off) ws += t;
            }
            wsum[lane] = ws;
        }
        __syncthreads();
        int cb = chunk_base;
        int woff = (wid > 0) ? wsum[wid - 1] : 0;
        if (i < NN) row_ptr[i] = cb + woff + s - v;
        int total = wsum[15];
        __syncthreads();
        if (threadIdx.x == 0) chunk_base = cb + total;
        __syncthreads();
    }
    if (threadIdx.x == 0) row_ptr[NN] = chunk_base;
}

__global__ void fill_kernel(const int* __restrict__ src, const int* __restrict__ dst,
                            const int* __restrict__ row_ptr, int* __restrict__ cursor,
                            int* __restrict__ col) {
    int e = blockIdx.x * blockDim.x + threadIdx.x;
    if (e < NE) {
        int d = dst[e];
        int pos = atomicAdd(&cursor[d], 1);
        col[row_ptr[d] + pos] = src[e];
    }
}

// ---------------------------------------------------------------------------
// GEMM v3:
//   if HAS_T: T[n,0:128] = (X[n,:] @ W1) * scale[n]
//   if HAS_P: P[n,0:64] += X[n,:] @ W2      (read-modify-write, blocks own rows)
// 256 thr, 64-row tile, KB=64, microtile 4 rows (rg+16*r) x 12 cols.
// Conflict-free LDS: X stride 68 (row groups -> banks 0/4/8/12), W 2-way.
// ---------------------------------------------------------------------------
template <bool HAS_T, bool HAS_P>
__global__ __launch_bounds__(256) void gemm_v3(
    const float* __restrict__ X, int ldx, int K,
    const float* __restrict__ W1,        // [K,128] (HAS_T)
    const float* __restrict__ W2,        // [K,64]  (HAS_P)
    const float* __restrict__ scale,     // nullptr => 1 (HAS_T epilogue)
    float* __restrict__ T,
    float* __restrict__ P,
    int nrows)
{
    constexpr int KB = 64;
    constexpr int TR = 64;
    constexpr int XS = 68;               // X LDS row stride

    __shared__ float Xl[TR * XS];
    __shared__ float W1l[HAS_T ? KB * 128 : 1];
    __shared__ float W2l[HAS_P ? KB * 64 : 1];

    const int tid = threadIdx.x;
    const int cg = tid & 15;             // 16 col groups
    const int rg = tid >> 4;             // 16 row groups
    const int row0 = blockIdx.x * TR;

    float accT[4][8];
    float accP[4][4];
#pragma unroll
    for (int r = 0; r < 4; r++) {
#pragma unroll
        for (int c = 0; c < 8; c++) accT[r][c] = 0.f;
#pragma unroll
        for (int c = 0; c < 4; c++) accP[r][c] = 0.f;
    }

    for (int kb = 0; kb < K; kb += KB) {
        if (HAS_T) {
            const float* w = W1 + (size_t)kb * 128;
#pragma unroll
            for (int i = 0; i < 8; i++) {
                int idx = (i * 256 + tid) * 4;
                *(float4*)(W1l + idx) = *(const float4*)(w + idx);
            }
        }
        if (HAS_P) {
            const float* w = W2 + (size_t)kb * 64;
#pragma unroll
            for (int i = 0; i < 4; i++) {
                int idx = (i * 256 + tid) * 4;
                *(float4*)(W2l + idx) = *(const float4*)(w + idx);
            }
        }
        {
#pragma unroll
            for (int i = 0; i < 4; i++) {
                int flat = i * 256 + tid;
                int r = flat >> 4;           // 16 float4 per row
                int k4 = flat & 15;
                int grow = row0 + r;
                float4 v = make_float4(0.f, 0.f, 0.f, 0.f);
                if (grow < nrows)
                    v = *(const float4*)(X + (size_t)grow * ldx + kb + k4 * 4);
                *(float4*)(Xl + r * XS + k4 * 4) = v;
            }
        }
        __syncthreads();

#pragma unroll 4
        for (int k = 0; k < KB; k += 4) {
            float4 xf[4];
#pragma unroll
            for (int r = 0; r < 4; r++)
                xf[r] = *(const float4*)(Xl + (rg + 16 * r) * XS + k);
            float4 w1a[4], w1b[4], w2[4];
#pragma unroll
            for (int kk = 0; kk < 4; kk++) {
                if (HAS_T) {
                    w1a[kk] = *(const float4*)(W1l + (k + kk) * 128 + cg * 4);
                    w1b[kk] = *(const float4*)(W1l + (k + kk) * 128 + cg * 4 + 64);
                }
                if (HAS_P)
                    w2[kk] = *(const float4*)(W2l + (k + kk) * 64 + cg * 4);
            }
#pragma unroll
            for (int r = 0; r < 4; r++) {
                float xv[4] = {xf[r].x, xf[r].y, xf[r].z, xf[r].w};
#pragma unroll
                for (int kk = 0; kk < 4; kk++) {
                    if (HAS_T) {
                        accT[r][0] = fmaf(xv[kk], w1a[kk].x, accT[r][0]);
                        accT[r][1] = fmaf(xv[kk], w1a[kk].y, accT[r][1]);
                        accT[r][2] = fmaf(xv[kk], w1a[kk].z, accT[r][2]);
                        accT[r][3] = fmaf(xv[kk], w1a[kk].w, accT[r][3]);
                        accT[r][4] = fmaf(xv[kk], w1b[kk].x, accT[r][4]);
                        accT[r][5] = fmaf(xv[kk], w1b[kk].y, accT[r][5]);
                        accT[r][6] = fmaf(xv[kk], w1b[kk].z, accT[r][6]);
                        accT[r][7] = fmaf(xv[kk], w1b[kk].w, accT[r][7]);
                    }
                    if (HAS_P) {
                        accP[r][0] = fmaf(xv[kk], w2[kk].x, accP[r][0]);
                        accP[r][1] = fmaf(xv[kk], w2[kk].y, accP[r][1]);
                        accP[r][2] = fmaf(xv[kk], w2[kk].z, accP[r][2]);
                        accP[r][3] = fmaf(xv[kk], w2[kk].w, accP[r][3]);
                    }
                }
            }
        }
        __syncthreads();
    }

#pragma unroll
    for (int r = 0; r < 4; r++) {
        int grow = row0 + rg + 16 * r;
        if (grow < nrows) {
            if (HAS_T) {
                float s = scale ? scale[grow] : 1.0f;
                float4 va = make_float4(accT[r][0] * s, accT[r][1] * s,
                                        accT[r][2] * s, accT[r][3] * s);
                float4 vb = make_float4(accT[r][4] * s, accT[r][5] * s,
                                        accT[r][6] * s, accT[r][7] * s);
                *(float4*)(T + (size_t)grow * 128 + cg * 4) = va;
                *(float4*)(T + (size_t)grow * 128 + cg * 4 + 64) = vb;
            }
            if (HAS_P) {
                float4 o = *(const float4*)(P + (size_t)grow * 64 + cg * 4);
                o.x += accP[r][0]; o.y += accP[r][1];
                o.z += accP[r][2]; o.w += accP[r][3];
                *(float4*)(P + (size_t)grow * 64 + cg * 4) = o;
            }
        }
    }
}

// ---------------------------------------------------------------------------
// CSR gather-reduce + epilogue:
//   Y[node,:] = act( (sum_{j in in(node)} T[col[j],:]) * scale[node] + bias )
// ---------------------------------------------------------------------------
template <int D, bool RELU>
__global__ void gather_kernel(const float* __restrict__ T,
                              const int* __restrict__ row_ptr,
                              const int* __restrict__ col,
                              const float* __restrict__ scale,
                              const float* __restrict__ bias,
                              float* __restrict__ Y, int ldy) {
    constexpr int Q = D / 4;
    int idx = blockIdx.x * blockDim.x + threadIdx.x;
    int node = idx / Q;
    int q = idx % Q;
    if (node >= NN) return;
    int beg = row_ptr[node];
    int end = row_ptr[node + 1];
    float4 acc = make_float4(0.f, 0.f, 0.f, 0.f);
    int j = beg;
    for (; j + 3 < end; j += 4) {
        int c0 = col[j], c1 = col[j + 1], c2 = col[j + 2], c3 = col[j + 3];
        float4 v0 = *(const float4*)(T + (size_t)c0 * D + q * 4);
        float4 v1 = *(const float4*)(T + (size_t)c1 * D + q * 4);
        float4 v2 = *(const float4*)(T + (size_t)c2 * D + q * 4);
        float4 v3 = *(const float4*)(T + (size_t)c3 * D + q * 4);
        acc.x += (v0.x + v1.x) + (v2.x + v3.x);
        acc.y += (v0.y + v1.y) + (v2.y + v3.y);
        acc.z += (v0.z + v1.z) + (v2.z + v3.z);
        acc.w += (v0.w + v1.w) + (v2.w + v3.w);
    }
    for (; j < end; j++) {
        int c0 = col[j];
        float4 v0 = *(const float4*)(T + (size_t)c0 * D + q * 4);
        acc.x += v0.x; acc.y += v0.y; acc.z += v0.z; acc.w += v0.w;
    }
    float s = scale ? scale[node] : 1.0f;
    float4 b = *(const float4*)(bias + q * 4);
    float4 h;
    h.x = fmaf(acc.x, s, b.x);
    h.y = fmaf(acc.y, s, b.y);
    h.z = fmaf(acc.z, s, b.z);
    h.w = fmaf(acc.w, s, b.w);
    if (RELU) {
        h.x = fmaxf(h.x, 0.f); h.y = fmaxf(h.y, 0.f);
        h.z = fmaxf(h.z, 0.f); h.w = fmaxf(h.w, 0.f);
    }
    *(float4*)(Y + (size_t)node * ldy + q * 4) = h;
}

// ---------------------------------------------------------------------------
extern "C" void kernel_launch(void* const* d_in, const int* in_sizes, int n_in,
                              void* d_out, int out_size, void* d_ws, size_t ws_size,
                              hipStream_t stream) {
    const float* feats = (const float*)d_in[0];
    const int*   src   = (const int*)d_in[1];
    const int*   dst   = (const int*)d_in[2];
    const float* W0    = (const float*)d_in[3];
    const float* b0    = (const float*)d_in[4];
    const float* Wh    = (const float*)d_in[5];   // [6,128,128]
    const float* bh    = (const float*)d_in[6];   // [6,128]
    const float* Wout  = (const float*)d_in[7];   // [896,64] = 7 blocks of [128,64]
    const float* bout  = (const float*)d_in[8];
    float* out = (float*)d_out;

    float* ws      = (float*)d_ws;
    float* inv_out = ws;                           // NN
    float* inv_in  = ws + NN;                      // NN
    float* t       = ws + 2 * NN;                  // NN*128
    float* ha      = t + (size_t)NN * D_H;         // NN*128
    float* hb      = ha + (size_t)NN * D_H;        // NN*128
    float* p       = hb + (size_t)NN * D_H;        // NN*64
    int* ibase     = (int*)(p + (size_t)NN * D_OUT);
    int* outdeg_i  = ibase;                        // NN
    int* indeg_i   = ibase + NN;                   // NN
    int* row_ptr   = ibase + 2 * NN;               // NN+1
    int* cursor    = ibase + 3 * NN + 1;           // NN
    int* col       = ibase + 4 * NN + 1;           // NE

    const int B = 256;
    const int gemm_blocks = (NN + 63) / 64;        // 469

    // ---- CSR build + norms + p init ----
    hipMemsetAsync(outdeg_i, 0, 2 * NN * sizeof(int), stream);
    hipMemsetAsync(cursor, 0, NN * sizeof(int), stream);
    hipMemsetAsync(p, 0, (size_t)NN * D_OUT * sizeof(float), stream);
    degree_kernel<<<(NE + B - 1) / B, B, 0, stream>>>(src, dst, outdeg_i, indeg_i);
    rsqrt_kernel<<<(2 * NN + B - 1) / B, B, 0, stream>>>(outdeg_i, inv_out, 2 * NN);
    scan_kernel<<<1, 1024, 0, stream>>>(indeg_i, row_ptr);
    fill_kernel<<<(NE + B - 1) / B, B, 0, stream>>>(src, dst, row_ptr, cursor, col);

    // ---- layer 0: t = (feats @ W0) * inv_out ; h0 = relu(gather*inv_in + b0)
    gemm_v3<true, false><<<gemm_blocks, 256, 0, stream>>>(
        feats, D_IN, D_IN, W0, nullptr, inv_out, t, nullptr, NN);
    gather_kernel<128, true><<<(NN * 32 + B - 1) / B, B, 0, stream>>>(
        t, row_ptr, col, inv_in, b0, ha, D_H);

    // ---- layers 1..6 fused with p += h_l @ Wout_l ----
    float* hcur = ha;
    float* hnext = hb;
    for (int l = 0; l < NL; l++) {
        gemm_v3<true, true><<<gemm_blocks, 256, 0, stream>>>(
            hcur, D_H, D_H, Wh + (size_t)l * D_H * D_H,
            Wout + (size_t)l * D_H * D_OUT, inv_out, t, p, NN);
        gather_kernel<128, true><<<(NN * 32 + B - 1) / B, B, 0, stream>>>(
            t, row_ptr, col, inv_in, bh + (size_t)l * D_H, hnext, D_H);
        float* tmp = hcur; hcur = hnext; hnext = tmp;
    }

    // ---- tail: p += h_6 @ Wout_6 ----
    gemm_v3<false, true><<<gemm_blocks, 256, 0, stream>>>(
        hcur, D_H, D_H, nullptr, Wout + (size_t)NL * D_H * D_OUT, nullptr,
        nullptr, p, NN);

    // ---- out = gather(p) + bout ----
    gather_kernel<64, false><<<(NN * 16 + B - 1) / B, B, 0, stream>>>(
        p, row_ptr, col, nullptr, bout, out, D_OUT);
}

// Round 5
// 477.961 us; speedup vs baseline: 1.5442x; 1.1294x over previous
//
#include <hip/hip_runtime.h>

#define NN 30000
#define NE 300000
#define D_IN 256
#define D_H 128
#define D_OUT 64
#define NL 6

typedef unsigned short ushort_t;
typedef unsigned int uint_t;

// fp32 -> bf16 round-to-nearest-even
static __device__ __forceinline__ ushort_t f2bf(float f) {
    uint_t u = __float_as_uint(f);
    u = (u + 0x7FFFu + ((u >> 16) & 1u)) >> 16;
    return (ushort_t)u;
}

// ---------------------------------------------------------------------------
__global__ void degree_kernel(const int* __restrict__ src, const int* __restrict__ dst,
                              int* __restrict__ outdeg, int* __restrict__ indeg) {
    int e = blockIdx.x * blockDim.x + threadIdx.x;
    if (e < NE) {
        atomicAdd(&outdeg[src[e]], 1);
        atomicAdd(&indeg[dst[e]], 1);
    }
}

__global__ void rsqrt_kernel(const int* __restrict__ deg, float* __restrict__ inv, int n) {
    int i = blockIdx.x * blockDim.x + threadIdx.x;
    if (i < n) {
        float d = (float)deg[i];
        inv[i] = rsqrtf(d < 1.0f ? 1.0f : d);
    }
}

// exclusive prefix scan of indeg[NN] -> row_ptr[NN+1]
__global__ __launch_bounds__(1024) void scan_kernel(const int* __restrict__ deg,
                                                    int* __restrict__ row_ptr) {
    __shared__ int wsum[16];
    __shared__ int chunk_base;
    if (threadIdx.x == 0) chunk_base = 0;
    __syncthreads();
    const int lane = threadIdx.x & 63;
    const int wid = threadIdx.x >> 6;
    for (int base = 0; base < NN; base += 1024) {
        int i = base + threadIdx.x;
        int v = (i < NN) ? deg[i] : 0;
        int s = v;
#pragma unroll
        for (int off = 1; off < 64; off <<= 1) {
            int t = __shfl_up(s, off, 64);
            if (lane >= off) s += t;
        }
        if (lane == 63) wsum[wid] = s;
        __syncthreads();
        if (wid == 0 && lane < 16) {
            int ws = wsum[lane];
#pragma unroll
            for (int off = 1; off < 16; off <<= 1) {
                int t = __shfl_up(ws, off, 64);
                if (lane >= off) ws += t;
            }
            wsum[lane] = ws;
        }
        __syncthreads();
        int cb = chunk_base;
        int woff = (wid > 0) ? wsum[wid - 1] : 0;
        if (i < NN) row_ptr[i] = cb + woff + s - v;
        int total = wsum[15];
        __syncthreads();
        if (threadIdx.x == 0) chunk_base = cb + total;
        __syncthreads();
    }
    if (threadIdx.x == 0) row_ptr[NN] = chunk_base;
}

__global__ void fill_kernel(const int* __restrict__ src, const int* __restrict__ dst,
                            const int* __restrict__ row_ptr, int* __restrict__ cursor,
                            int* __restrict__ col) {
    int e = blockIdx.x * blockDim.x + threadIdx.x;
    if (e < NE) {
        int d = dst[e];
        int pos = atomicAdd(&cursor[d], 1);
        col[row_ptr[d] + pos] = src[e];
    }
}

// ---------------------------------------------------------------------------
// GEMM v3 (fp32 compute):
//   if HAS_T: Tb[n,0:128] = bf16( (X[n,:] @ W1) * scale[n] )
//   if HAS_P: P[n,0:64] += X[n,:] @ W2      (fp32 RMW, blocks own rows)
// ---------------------------------------------------------------------------
template <bool HAS_T, bool HAS_P>
__global__ __launch_bounds__(256) void gemm_v3(
    const float* __restrict__ X, int ldx, int K,
    const float* __restrict__ W1,        // [K,128]
    const float* __restrict__ W2,        // [K,64]
    const float* __restrict__ scale,
    ushort_t* __restrict__ Tb,           // bf16 out [NN,128]
    float* __restrict__ P,
    int nrows)
{
    constexpr int KB = 64;
    constexpr int TR = 64;
    constexpr int XS = 68;

    __shared__ float Xl[TR * XS];
    __shared__ float W1l[HAS_T ? KB * 128 : 1];
    __shared__ float W2l[HAS_P ? KB * 64 : 1];

    const int tid = threadIdx.x;
    const int cg = tid & 15;
    const int rg = tid >> 4;
    const int row0 = blockIdx.x * TR;

    float accT[4][8];
    float accP[4][4];
#pragma unroll
    for (int r = 0; r < 4; r++) {
#pragma unroll
        for (int c = 0; c < 8; c++) accT[r][c] = 0.f;
#pragma unroll
        for (int c = 0; c < 4; c++) accP[r][c] = 0.f;
    }

    for (int kb = 0; kb < K; kb += KB) {
        if (HAS_T) {
            const float* w = W1 + (size_t)kb * 128;
#pragma unroll
            for (int i = 0; i < 8; i++) {
                int idx = (i * 256 + tid) * 4;
                *(float4*)(W1l + idx) = *(const float4*)(w + idx);
            }
        }
        if (HAS_P) {
            const float* w = W2 + (size_t)kb * 64;
#pragma unroll
            for (int i = 0; i < 4; i++) {
                int idx = (i * 256 + tid) * 4;
                *(float4*)(W2l + idx) = *(const float4*)(w + idx);
            }
        }
        {
#pragma unroll
            for (int i = 0; i < 4; i++) {
                int flat = i * 256 + tid;
                int r = flat >> 4;
                int k4 = flat & 15;
                int grow = row0 + r;
                float4 v = make_float4(0.f, 0.f, 0.f, 0.f);
                if (grow < nrows)
                    v = *(const float4*)(X + (size_t)grow * ldx + kb + k4 * 4);
                *(float4*)(Xl + r * XS + k4 * 4) = v;
            }
        }
        __syncthreads();

#pragma unroll 4
        for (int k = 0; k < KB; k += 4) {
            float4 xf[4];
#pragma unroll
            for (int r = 0; r < 4; r++)
                xf[r] = *(const float4*)(Xl + (rg + 16 * r) * XS + k);
            float4 w1a[4], w1b[4], w2[4];
#pragma unroll
            for (int kk = 0; kk < 4; kk++) {
                if (HAS_T) {
                    w1a[kk] = *(const float4*)(W1l + (k + kk) * 128 + cg * 4);
                    w1b[kk] = *(const float4*)(W1l + (k + kk) * 128 + cg * 4 + 64);
                }
                if (HAS_P)
                    w2[kk] = *(const float4*)(W2l + (k + kk) * 64 + cg * 4);
            }
#pragma unroll
            for (int r = 0; r < 4; r++) {
                float xv[4] = {xf[r].x, xf[r].y, xf[r].z, xf[r].w};
#pragma unroll
                for (int kk = 0; kk < 4; kk++) {
                    if (HAS_T) {
                        accT[r][0] = fmaf(xv[kk], w1a[kk].x, accT[r][0]);
                        accT[r][1] = fmaf(xv[kk], w1a[kk].y, accT[r][1]);
                        accT[r][2] = fmaf(xv[kk], w1a[kk].z, accT[r][2]);
                        accT[r][3] = fmaf(xv[kk], w1a[kk].w, accT[r][3]);
                        accT[r][4] = fmaf(xv[kk], w1b[kk].x, accT[r][4]);
                        accT[r][5] = fmaf(xv[kk], w1b[kk].y, accT[r][5]);
                        accT[r][6] = fmaf(xv[kk], w1b[kk].z, accT[r][6]);
                        accT[r][7] = fmaf(xv[kk], w1b[kk].w, accT[r][7]);
                    }
                    if (HAS_P) {
                        accP[r][0] = fmaf(xv[kk], w2[kk].x, accP[r][0]);
                        accP[r][1] = fmaf(xv[kk], w2[kk].y, accP[r][1]);
                        accP[r][2] = fmaf(xv[kk], w2[kk].z, accP[r][2]);
                        accP[r][3] = fmaf(xv[kk], w2[kk].w, accP[r][3]);
                    }
                }
            }
        }
        __syncthreads();
    }

#pragma unroll
    for (int r = 0; r < 4; r++) {
        int grow = row0 + rg + 16 * r;
        if (grow < nrows) {
            if (HAS_T) {
                float s = scale ? scale[grow] : 1.0f;
                ushort_t pa[4], pb[4];
#pragma unroll
                for (int c = 0; c < 4; c++) {
                    pa[c] = f2bf(accT[r][c] * s);
                    pb[c] = f2bf(accT[r][c + 4] * s);
                }
                *(ushort4*)(Tb + (size_t)grow * 128 + cg * 4) =
                    make_ushort4(pa[0], pa[1], pa[2], pa[3]);
                *(ushort4*)(Tb + (size_t)grow * 128 + 64 + cg * 4) =
                    make_ushort4(pb[0], pb[1], pb[2], pb[3]);
            }
            if (HAS_P) {
                float4 o = *(const float4*)(P + (size_t)grow * 64 + cg * 4);
                o.x += accP[r][0]; o.y += accP[r][1];
                o.z += accP[r][2]; o.w += accP[r][3];
                *(float4*)(P + (size_t)grow * 64 + cg * 4) = o;
            }
        }
    }
}

// ---------------------------------------------------------------------------
// bf16 CSR gather: h[node, 0:128] = relu( sum T[col[j],:] * scale[node] + bias )
// thread = (node, q in 0..15); loads uint4 = 8 bf16 per edge.
// ---------------------------------------------------------------------------
__global__ __launch_bounds__(256) void gather_bf16_kernel(
    const ushort_t* __restrict__ Tb,
    const int* __restrict__ row_ptr,
    const int* __restrict__ col,
    const float* __restrict__ scale,
    const float* __restrict__ bias,
    float* __restrict__ Y) {           // [NN,128] fp32
    int idx = blockIdx.x * blockDim.x + threadIdx.x;
    int node = idx >> 4;
    int q = idx & 15;
    if (node >= NN) return;
    int beg = row_ptr[node];
    int end = row_ptr[node + 1];
    const uint_t* T32 = (const uint_t*)Tb;   // row = 64 uints
    float acc[8];
#pragma unroll
    for (int i = 0; i < 8; i++) acc[i] = 0.f;

    int j = beg;
    for (; j + 1 < end; j += 2) {
        int c0 = col[j], c1 = col[j + 1];
        uint4 u0 = *(const uint4*)(T32 + (size_t)c0 * 64 + q * 4);
        uint4 u1 = *(const uint4*)(T32 + (size_t)c1 * 64 + q * 4);
        uint_t w0[4] = {u0.x, u0.y, u0.z, u0.w};
        uint_t w1[4] = {u1.x, u1.y, u1.z, u1.w};
#pragma unroll
        for (int i = 0; i < 4; i++) {
            acc[2 * i]     += __uint_as_float(w0[i] << 16) + __uint_as_float(w1[i] << 16);
            acc[2 * i + 1] += __uint_as_float(w0[i] & 0xFFFF0000u) + __uint_as_float(w1[i] & 0xFFFF0000u);
        }
    }
    if (j < end) {
        int c0 = col[j];
        uint4 u0 = *(const uint4*)(T32 + (size_t)c0 * 64 + q * 4);
        uint_t w0[4] = {u0.x, u0.y, u0.z, u0.w};
#pragma unroll
        for (int i = 0; i < 4; i++) {
            acc[2 * i]     += __uint_as_float(w0[i] << 16);
            acc[2 * i + 1] += __uint_as_float(w0[i] & 0xFFFF0000u);
        }
    }

    float s = scale[node];
    float4 b0 = *(const float4*)(bias + q * 8);
    float4 b1 = *(const float4*)(bias + q * 8 + 4);
    float4 h0, h1;
    h0.x = fmaxf(fmaf(acc[0], s, b0.x), 0.f);
    h0.y = fmaxf(fmaf(acc[1], s, b0.y), 0.f);
    h0.z = fmaxf(fmaf(acc[2], s, b0.z), 0.f);
    h0.w = fmaxf(fmaf(acc[3], s, b0.w), 0.f);
    h1.x = fmaxf(fmaf(acc[4], s, b1.x), 0.f);
    h1.y = fmaxf(fmaf(acc[5], s, b1.y), 0.f);
    h1.z = fmaxf(fmaf(acc[6], s, b1.z), 0.f);
    h1.w = fmaxf(fmaf(acc[7], s, b1.w), 0.f);
    *(float4*)(Y + (size_t)node * 128 + q * 8) = h0;
    *(float4*)(Y + (size_t)node * 128 + q * 8 + 4) = h1;
}

// fp32 final gather: out[node,0:64] = sum p[col[j],:] + bout
__global__ __launch_bounds__(256) void gather_f32_kernel(
    const float* __restrict__ P,
    const int* __restrict__ row_ptr,
    const int* __restrict__ col,
    const float* __restrict__ bias,
    float* __restrict__ Y) {
    int idx = blockIdx.x * blockDim.x + threadIdx.x;
    int node = idx >> 4;
    int q = idx & 15;
    if (node >= NN) return;
    int beg = row_ptr[node];
    int end = row_ptr[node + 1];
    float4 acc = make_float4(0.f, 0.f, 0.f, 0.f);
    int j = beg;
    for (; j + 1 < end; j += 2) {
        int c0 = col[j], c1 = col[j + 1];
        float4 v0 = *(const float4*)(P + (size_t)c0 * 64 + q * 4);
        float4 v1 = *(const float4*)(P + (size_t)c1 * 64 + q * 4);
        acc.x += v0.x + v1.x; acc.y += v0.y + v1.y;
        acc.z += v0.z + v1.z; acc.w += v0.w + v1.w;
    }
    if (j < end) {
        int c0 = col[j];
        float4 v0 = *(const float4*)(P + (size_t)c0 * 64 + q * 4);
        acc.x += v0.x; acc.y += v0.y; acc.z += v0.z; acc.w += v0.w;
    }
    float4 b = *(const float4*)(bias + q * 4);
    acc.x += b.x; acc.y += b.y; acc.z += b.z; acc.w += b.w;
    *(float4*)(Y + (size_t)node * 64 + q * 4) = acc;
}

// ---------------------------------------------------------------------------
extern "C" void kernel_launch(void* const* d_in, const int* in_sizes, int n_in,
                              void* d_out, int out_size, void* d_ws, size_t ws_size,
                              hipStream_t stream) {
    const float* feats = (const float*)d_in[0];
    const int*   src   = (const int*)d_in[1];
    const int*   dst   = (const int*)d_in[2];
    const float* W0    = (const float*)d_in[3];
    const float* b0    = (const float*)d_in[4];
    const float* Wh    = (const float*)d_in[5];
    const float* bh    = (const float*)d_in[6];
    const float* Wout  = (const float*)d_in[7];   // [896,64] = 7 x [128,64]
    const float* bout  = (const float*)d_in[8];
    float* out = (float*)d_out;

    float* ws      = (float*)d_ws;
    float* inv_out = ws;                           // NN
    float* inv_in  = ws + NN;                      // NN
    ushort_t* tb   = (ushort_t*)(ws + 2 * NN);     // NN*128 bf16 = NN*64 floats
    float* ha      = ws + 2 * NN + (size_t)NN * 64;   // NN*128
    float* hb      = ha + (size_t)NN * D_H;        // NN*128
    float* p       = hb + (size_t)NN * D_H;        // NN*64
    int* ibase     = (int*)(p + (size_t)NN * D_OUT);
    int* outdeg_i  = ibase;                        // NN
    int* indeg_i   = ibase + NN;                   // NN
    int* row_ptr   = ibase + 2 * NN;               // NN+1
    int* cursor    = ibase + 3 * NN + 1;           // NN
    int* col       = ibase + 4 * NN + 1;           // NE

    const int B = 256;
    const int gemm_blocks = (NN + 63) / 64;        // 469
    const int gather_blocks = (NN * 16 + B - 1) / B;

    // ---- CSR build + norms + p init ----
    hipMemsetAsync(outdeg_i, 0, 2 * NN * sizeof(int), stream);
    hipMemsetAsync(cursor, 0, NN * sizeof(int), stream);
    hipMemsetAsync(p, 0, (size_t)NN * D_OUT * sizeof(float), stream);
    degree_kernel<<<(NE + B - 1) / B, B, 0, stream>>>(src, dst, outdeg_i, indeg_i);
    rsqrt_kernel<<<(2 * NN + B - 1) / B, B, 0, stream>>>(outdeg_i, inv_out, 2 * NN);
    scan_kernel<<<1, 1024, 0, stream>>>(indeg_i, row_ptr);
    fill_kernel<<<(NE + B - 1) / B, B, 0, stream>>>(src, dst, row_ptr, cursor, col);

    // ---- layer 0 ----
    gemm_v3<true, false><<<gemm_blocks, 256, 0, stream>>>(
        feats, D_IN, D_IN, W0, nullptr, inv_out, tb, nullptr, NN);
    gather_bf16_kernel<<<gather_blocks, B, 0, stream>>>(
        tb, row_ptr, col, inv_in, b0, ha);

    // ---- layers 1..6 fused with p += h_l @ Wout_l ----
    float* hcur = ha;
    float* hnext = hb;
    for (int l = 0; l < NL; l++) {
        gemm_v3<true, true><<<gemm_blocks, 256, 0, stream>>>(
            hcur, D_H, D_H, Wh + (size_t)l * D_H * D_H,
            Wout + (size_t)l * D_H * D_OUT, inv_out, tb, p, NN);
        gather_bf16_kernel<<<gather_blocks, B, 0, stream>>>(
            tb, row_ptr, col, inv_in, bh + (size_t)l * D_H, hnext);
        float* tmp = hcur; hcur = hnext; hnext = tmp;
    }

    // ---- tail: p += h_6 @ Wout_6 ----
    gemm_v3<false, true><<<gemm_blocks, 256, 0, stream>>>(
        hcur, D_H, D_H, nullptr, Wout + (size_t)NL * D_H * D_OUT, nullptr,
        nullptr, p, NN);

    // ---- out = gather(p) + bout ----
    gather_f32_kernel<<<gather_blocks, B, 0, stream>>>(p, row_ptr, col, bout, out);
}

// Round 6
// 384.542 us; speedup vs baseline: 1.9193x; 1.2429x over previous
//
#include <hip/hip_runtime.h>

#define NN 30000
#define NE 300000
#define D_IN 256
#define D_H 128
#define D_OUT 64
#define NL 6

typedef unsigned short ushort_t;
typedef unsigned int uint_t;
typedef __attribute__((ext_vector_type(8))) short sh8;
typedef __attribute__((ext_vector_type(4))) float f4;

// fp32 -> bf16 round-to-nearest-even
static __device__ __forceinline__ ushort_t f2bf(float f) {
    uint_t u = __float_as_uint(f);
    u = (u + 0x7FFFu + ((u >> 16) & 1u)) >> 16;
    return (ushort_t)u;
}

// ---------------------------------------------------------------------------
__global__ void degree_kernel(const int* __restrict__ src, const int* __restrict__ dst,
                              int* __restrict__ outdeg, int* __restrict__ indeg) {
    int e = blockIdx.x * blockDim.x + threadIdx.x;
    if (e < NE) {
        atomicAdd(&outdeg[src[e]], 1);
        atomicAdd(&indeg[dst[e]], 1);
    }
}

__global__ void rsqrt_kernel(const int* __restrict__ deg, float* __restrict__ inv, int n) {
    int i = blockIdx.x * blockDim.x + threadIdx.x;
    if (i < n) {
        float d = (float)deg[i];
        inv[i] = rsqrtf(d < 1.0f ? 1.0f : d);
    }
}

// exclusive prefix scan of indeg[NN] -> row_ptr[NN+1]
__global__ __launch_bounds__(1024) void scan_kernel(const int* __restrict__ deg,
                                                    int* __restrict__ row_ptr) {
    __shared__ int wsum[16];
    __shared__ int chunk_base;
    if (threadIdx.x == 0) chunk_base = 0;
    __syncthreads();
    const int lane = threadIdx.x & 63;
    const int wid = threadIdx.x >> 6;
    for (int base = 0; base < NN; base += 1024) {
        int i = base + threadIdx.x;
        int v = (i < NN) ? deg[i] : 0;
        int s = v;
#pragma unroll
        for (int off = 1; off < 64; off <<= 1) {
            int t = __shfl_up(s, off, 64);
            if (lane >= off) s += t;
        }
        if (lane == 63) wsum[wid] = s;
        __syncthreads();
        if (wid == 0 && lane < 16) {
            int ws = wsum[lane];
#pragma unroll
            for (int off = 1; off < 16; off <<= 1) {
                int t = __shfl_up(ws, off, 64);
                if (lane >= off) ws += t;
            }
            wsum[lane] = ws;
        }
        __syncthreads();
        int cb = chunk_base;
        int woff = (wid > 0) ? wsum[wid - 1] : 0;
        if (i < NN) row_ptr[i] = cb + woff + s - v;
        int total = wsum[15];
        __syncthreads();
        if (threadIdx.x == 0) chunk_base = cb + total;
        __syncthreads();
    }
    if (threadIdx.x == 0) row_ptr[NN] = chunk_base;
}

__global__ void fill_kernel(const int* __restrict__ src, const int* __restrict__ dst,
                            const int* __restrict__ row_ptr, int* __restrict__ cursor,
                            int* __restrict__ col) {
    int e = blockIdx.x * blockDim.x + threadIdx.x;
    if (e < NE) {
        int d = dst[e];
        int pos = atomicAdd(&cursor[d], 1);
        col[row_ptr[d] + pos] = src[e];
    }
}

// ---------------------------------------------------------------------------
// feats fp32 -> bf16 (flat)
__global__ void featconv_kernel(const float* __restrict__ F, ushort_t* __restrict__ Fb) {
    int i = blockIdx.x * blockDim.x + threadIdx.x;   // over NN*256/8
    if (i >= NN * D_IN / 8) return;
    float4 a = *(const float4*)(F + (size_t)i * 8);
    float4 b = *(const float4*)(F + (size_t)i * 8 + 4);
    uint4 o;
    o.x = (uint_t)f2bf(a.x) | ((uint_t)f2bf(a.y) << 16);
    o.y = (uint_t)f2bf(a.z) | ((uint_t)f2bf(a.w) << 16);
    o.z = (uint_t)f2bf(b.x) | ((uint_t)f2bf(b.y) << 16);
    o.w = (uint_t)f2bf(b.z) | ((uint_t)f2bf(b.w) << 16);
    *(uint4*)(Fb + (size_t)i * 8) = o;
}

// ---------------------------------------------------------------------------
// Pack all weights into MFMA B-fragment order, bf16.
// Fragment f (= ct*KF + kt), lane l, j=0..7 holds
//   W[kt*32 + (l>>4)*8 + j][ct*16 + (l&15)]
// Segments: W0 (K=256,M=128,64 frags) | Wh[l] (K=128,M=128,32 frags x6)
//           | Wout_l (K=128,M=64,16 frags x7).  Total 368 frags.
// ---------------------------------------------------------------------------
__global__ void packw_kernel(const float* __restrict__ W0,
                             const float* __restrict__ Wh,
                             const float* __restrict__ Wout,
                             ushort_t* __restrict__ W0p,
                             ushort_t* __restrict__ Whp,
                             ushort_t* __restrict__ Woutp) {
    int g = blockIdx.x * blockDim.x + threadIdx.x;
    int frag = g >> 6;
    int lane = g & 63;
    if (frag >= 368) return;
    const float* srcw;
    ushort_t* dstp;
    int fl, KF, M;
    if (frag < 64) {                     // W0
        fl = frag; KF = 8; M = 128;
        srcw = W0;
        dstp = W0p;
    } else if (frag < 64 + 192) {        // Wh
        int f2 = frag - 64;
        int l = f2 / 32; fl = f2 % 32; KF = 4; M = 128;
        srcw = Wh + (size_t)l * D_H * D_H;
        dstp = Whp + (size_t)l * 32 * 512;
    } else {                             // Wout blocks
        int f2 = frag - 256;
        int l = f2 / 16; fl = f2 % 16; KF = 4; M = 64;
        srcw = Wout + (size_t)l * D_H * D_OUT;
        dstp = Woutp + (size_t)l * 16 * 512;
    }
    int ct = fl / KF;
    int kt = fl % KF;
    int krow = kt * 32 + (lane >> 4) * 8;
    int cidx = ct * 16 + (lane & 15);
    ushort_t tmp[8];
#pragma unroll
    for (int j = 0; j < 8; j++)
        tmp[j] = f2bf(srcw[(size_t)(krow + j) * M + cidx]);
    uint4 o;
    o.x = (uint_t)tmp[0] | ((uint_t)tmp[1] << 16);
    o.y = (uint_t)tmp[2] | ((uint_t)tmp[3] << 16);
    o.z = (uint_t)tmp[4] | ((uint_t)tmp[5] << 16);
    o.w = (uint_t)tmp[6] | ((uint_t)tmp[7] << 16);
    *(uint4*)(dstp + (size_t)fl * 512 + lane * 8) = o;
}

// ---------------------------------------------------------------------------
// MFMA GEMM (bf16 in, no LDS):
//   if HAS_T: Tb[n,0:128] = bf16( (X @ W1) * scale[n] )
//   if HAS_P: P[n,0:64]  += X @ W2   (fp32 RMW; blocks own rows)
// block = 256 thr = 4 waves = 2 row-groups(16 rows) x 2 col-groups.
// A-frags straight from global (coalesced); B-frags from packed weights (L2).
// ---------------------------------------------------------------------------
template <int KF, bool HAS_T, bool HAS_P>
__global__ __launch_bounds__(256) void gemm_mfma(
    const ushort_t* __restrict__ Xb,    // [nrows, KF*32] bf16
    const ushort_t* __restrict__ W1p,   // packed [8*KF frags]
    const ushort_t* __restrict__ W2p,   // packed [4*KF frags]
    const float* __restrict__ scale,
    ushort_t* __restrict__ Tb,
    float* __restrict__ P,
    int nrows)
{
    constexpr int K = KF * 32;
    const int lane = threadIdx.x & 63;
    const int w = threadIdx.x >> 6;
    const int rg = w >> 1;
    const int cgrp = w & 1;
    const int row0 = blockIdx.x * 32 + rg * 16;

    // --- A fragments for this wave's 16 rows ---
    int arow = row0 + (lane & 15);
    if (arow >= nrows) arow = nrows - 1;
    const ushort_t* xr = Xb + (size_t)arow * K + ((lane >> 4) * 8);
    sh8 a[KF];
#pragma unroll
    for (int kt = 0; kt < KF; kt++)
        a[kt] = *(const sh8*)(xr + kt * 32);

    // --- C rows for this lane ---
    const int crow0 = row0 + (lane >> 4) * 4;

    if (HAS_T) {
        float s[4];
#pragma unroll
        for (int r = 0; r < 4; r++) {
            int rw = crow0 + r;
            s[r] = scale[rw < nrows ? rw : nrows - 1];
        }
#pragma unroll
        for (int i = 0; i < 4; i++) {
            int ct = cgrp * 4 + i;
            f4 acc = {0.f, 0.f, 0.f, 0.f};
            const ushort_t* wp = W1p + ((size_t)(ct * KF) << 9) + lane * 8;
#pragma unroll
            for (int kt = 0; kt < KF; kt++)
                acc = __builtin_amdgcn_mfma_f32_16x16x32_bf16(
                    a[kt], *(const sh8*)(wp + ((size_t)kt << 9)), acc, 0, 0, 0);
            int colb = ct * 16 + (lane & 15);
#pragma unroll
            for (int r = 0; r < 4; r++) {
                int rw = crow0 + r;
                if (rw < nrows)
                    Tb[(size_t)rw * 128 + colb] = f2bf(acc[r] * s[r]);
            }
        }
    }
    if (HAS_P) {
#pragma unroll
        for (int i = 0; i < 2; i++) {
            int ct = cgrp * 2 + i;
            f4 acc = {0.f, 0.f, 0.f, 0.f};
            const ushort_t* wp = W2p + ((size_t)(ct * KF) << 9) + lane * 8;
#pragma unroll
            for (int kt = 0; kt < KF; kt++)
                acc = __builtin_amdgcn_mfma_f32_16x16x32_bf16(
                    a[kt], *(const sh8*)(wp + ((size_t)kt << 9)), acc, 0, 0, 0);
            int colb = ct * 16 + (lane & 15);
#pragma unroll
            for (int r = 0; r < 4; r++) {
                int rw = crow0 + r;
                if (rw < nrows) {
                    float* pp = P + (size_t)rw * 64 + colb;
                    *pp += acc[r];
                }
            }
        }
    }
}

// ---------------------------------------------------------------------------
// bf16 CSR gather: Yb[node,0:128] = bf16(relu( sum Tb[col[j],:] * scale + bias ))
// thread = (node, q in 0..15); uint4 = 8 bf16 per edge row segment.
// ---------------------------------------------------------------------------
__global__ __launch_bounds__(256) void gather_bf16_kernel(
    const ushort_t* __restrict__ Tb,
    const int* __restrict__ row_ptr,
    const int* __restrict__ col,
    const float* __restrict__ scale,
    const float* __restrict__ bias,
    ushort_t* __restrict__ Yb) {        // [NN,128] bf16
    int idx = blockIdx.x * blockDim.x + threadIdx.x;
    int node = idx >> 4;
    int q = idx & 15;
    if (node >= NN) return;
    int beg = row_ptr[node];
    int end = row_ptr[node + 1];
    const uint_t* T32 = (const uint_t*)Tb;   // row = 64 uints
    float acc[8];
#pragma unroll
    for (int i = 0; i < 8; i++) acc[i] = 0.f;

    int j = beg;
    for (; j + 1 < end; j += 2) {
        int c0 = col[j], c1 = col[j + 1];
        uint4 u0 = *(const uint4*)(T32 + (size_t)c0 * 64 + q * 4);
        uint4 u1 = *(const uint4*)(T32 + (size_t)c1 * 64 + q * 4);
        uint_t w0[4] = {u0.x, u0.y, u0.z, u0.w};
        uint_t w1[4] = {u1.x, u1.y, u1.z, u1.w};
#pragma unroll
        for (int i = 0; i < 4; i++) {
            acc[2 * i]     += __uint_as_float(w0[i] << 16) + __uint_as_float(w1[i] << 16);
            acc[2 * i + 1] += __uint_as_float(w0[i] & 0xFFFF0000u) + __uint_as_float(w1[i] & 0xFFFF0000u);
        }
    }
    if (j < end) {
        int c0 = col[j];
        uint4 u0 = *(const uint4*)(T32 + (size_t)c0 * 64 + q * 4);
        uint_t w0[4] = {u0.x, u0.y, u0.z, u0.w};
#pragma unroll
        for (int i = 0; i < 4; i++) {
            acc[2 * i]     += __uint_as_float(w0[i] << 16);
            acc[2 * i + 1] += __uint_as_float(w0[i] & 0xFFFF0000u);
        }
    }

    float s = scale[node];
    float h[8];
#pragma unroll
    for (int i = 0; i < 8; i++)
        h[i] = fmaxf(fmaf(acc[i], s, bias[q * 8 + i]), 0.f);
    uint4 o;
    o.x = (uint_t)f2bf(h[0]) | ((uint_t)f2bf(h[1]) << 16);
    o.y = (uint_t)f2bf(h[2]) | ((uint_t)f2bf(h[3]) << 16);
    o.z = (uint_t)f2bf(h[4]) | ((uint_t)f2bf(h[5]) << 16);
    o.w = (uint_t)f2bf(h[6]) | ((uint_t)f2bf(h[7]) << 16);
    *(uint4*)(Yb + (size_t)node * 128 + q * 8) = o;
}

// fp32 final gather: out[node,0:64] = sum p[col[j],:] + bout
__global__ __launch_bounds__(256) void gather_f32_kernel(
    const float* __restrict__ P,
    const int* __restrict__ row_ptr,
    const int* __restrict__ col,
    const float* __restrict__ bias,
    float* __restrict__ Y) {
    int idx = blockIdx.x * blockDim.x + threadIdx.x;
    int node = idx >> 4;
    int q = idx & 15;
    if (node >= NN) return;
    int beg = row_ptr[node];
    int end = row_ptr[node + 1];
    float4 acc = make_float4(0.f, 0.f, 0.f, 0.f);
    int j = beg;
    for (; j + 1 < end; j += 2) {
        int c0 = col[j], c1 = col[j + 1];
        float4 v0 = *(const float4*)(P + (size_t)c0 * 64 + q * 4);
        float4 v1 = *(const float4*)(P + (size_t)c1 * 64 + q * 4);
        acc.x += v0.x + v1.x; acc.y += v0.y + v1.y;
        acc.z += v0.z + v1.z; acc.w += v0.w + v1.w;
    }
    if (j < end) {
        int c0 = col[j];
        float4 v0 = *(const float4*)(P + (size_t)c0 * 64 + q * 4);
        acc.x += v0.x; acc.y += v0.y; acc.z += v0.z; acc.w += v0.w;
    }
    float4 b = *(const float4*)(bias + q * 4);
    acc.x += b.x; acc.y += b.y; acc.z += b.z; acc.w += b.w;
    *(float4*)(Y + (size_t)node * 64 + q * 4) = acc;
}

// ---------------------------------------------------------------------------
extern "C" void kernel_launch(void* const* d_in, const int* in_sizes, int n_in,
                              void* d_out, int out_size, void* d_ws, size_t ws_size,
                              hipStream_t stream) {
    const float* feats = (const float*)d_in[0];
    const int*   src   = (const int*)d_in[1];
    const int*   dst   = (const int*)d_in[2];
    const float* W0    = (const float*)d_in[3];
    const float* b0    = (const float*)d_in[4];
    const float* Wh    = (const float*)d_in[5];
    const float* bh    = (const float*)d_in[6];
    const float* Wout  = (const float*)d_in[7];   // [896,64] = 7 x [128,64]
    const float* bout  = (const float*)d_in[8];
    float* out = (float*)d_out;

    float* ws      = (float*)d_ws;
    float* inv_out = ws;                              // NN
    float* inv_in  = ws + NN;                         // NN
    float* p       = ws + 2 * NN;                     // NN*64 fp32
    ushort_t* tb   = (ushort_t*)(p + (size_t)NN * 64);      // NN*128 bf16
    ushort_t* ha   = tb + (size_t)NN * 128;           // NN*128 bf16
    ushort_t* hb   = ha + (size_t)NN * 128;           // NN*128 bf16
    ushort_t* fb   = hb + (size_t)NN * 128;           // NN*256 bf16
    ushort_t* w0p  = fb + (size_t)NN * 256;           // 64*512
    ushort_t* whp  = w0p + 64 * 512;                  // 192*512
    ushort_t* wop  = whp + 192 * 512;                 // 112*512
    int* ibase     = (int*)(wop + 112 * 512);
    int* outdeg_i  = ibase;                           // NN
    int* indeg_i   = ibase + NN;                      // NN
    int* row_ptr   = ibase + 2 * NN;                  // NN+1
    int* cursor    = ibase + 3 * NN + 1;              // NN
    int* col       = ibase + 4 * NN + 1;              // NE

    const int B = 256;
    const int gemm_blocks = (NN + 31) / 32;           // 938
    const int gather_blocks = (NN * 16 + B - 1) / B;

    // ---- CSR build + norms + conversions + packing ----
    hipMemsetAsync(outdeg_i, 0, 2 * NN * sizeof(int), stream);
    hipMemsetAsync(cursor, 0, NN * sizeof(int), stream);
    hipMemsetAsync(p, 0, (size_t)NN * D_OUT * sizeof(float), stream);
    degree_kernel<<<(NE + B - 1) / B, B, 0, stream>>>(src, dst, outdeg_i, indeg_i);
    rsqrt_kernel<<<(2 * NN + B - 1) / B, B, 0, stream>>>(outdeg_i, inv_out, 2 * NN);
    scan_kernel<<<1, 1024, 0, stream>>>(indeg_i, row_ptr);
    fill_kernel<<<(NE + B - 1) / B, B, 0, stream>>>(src, dst, row_ptr, cursor, col);
    featconv_kernel<<<(NN * D_IN / 8 + B - 1) / B, B, 0, stream>>>(feats, fb);
    packw_kernel<<<(368 * 64 + B - 1) / B, B, 0, stream>>>(W0, Wh, Wout, w0p, whp, wop);

    // ---- layer 0 ----
    gemm_mfma<8, true, false><<<gemm_blocks, 256, 0, stream>>>(
        fb, w0p, nullptr, inv_out, tb, nullptr, NN);
    gather_bf16_kernel<<<gather_blocks, B, 0, stream>>>(
        tb, row_ptr, col, inv_in, b0, ha);

    // ---- layers 1..6 fused with p += h_l @ Wout_l ----
    ushort_t* hcur = ha;
    ushort_t* hnext = hb;
    for (int l = 0; l < NL; l++) {
        gemm_mfma<4, true, true><<<gemm_blocks, 256, 0, stream>>>(
            hcur, whp + (size_t)l * 32 * 512, wop + (size_t)l * 16 * 512,
            inv_out, tb, p, NN);
        gather_bf16_kernel<<<gather_blocks, B, 0, stream>>>(
            tb, row_ptr, col, inv_in, bh + (size_t)l * D_H, hnext);
        ushort_t* tmp = hcur; hcur = hnext; hnext = tmp;
    }

    // ---- tail: p += h_6 @ Wout_6 ----
    gemm_mfma<4, false, true><<<gemm_blocks, 256, 0, stream>>>(
        hcur, nullptr, wop + (size_t)NL * 16 * 512, nullptr, nullptr, p, NN);

    // ---- out = gather(p) + bout ----
    gather_f32_kernel<<<gather_blocks, B, 0, stream>>>(p, row_ptr, col, bout, out);
}

// Round 7
// 376.198 us; speedup vs baseline: 1.9619x; 1.0222x over previous
//
#include <hip/hip_runtime.h>

#define NN 30000
#define NE 300000
#define D_IN 256
#define D_H 128
#define D_OUT 64
#define NL 6

typedef unsigned short ushort_t;
typedef unsigned int uint_t;
typedef __attribute__((ext_vector_type(8))) short sh8;
typedef __attribute__((ext_vector_type(4))) float f4;

// fp32 -> bf16 round-to-nearest-even
static __device__ __forceinline__ ushort_t f2bf(float f) {
    uint_t u = __float_as_uint(f);
    u = (u + 0x7FFFu + ((u >> 16) & 1u)) >> 16;
    return (ushort_t)u;
}

// ---------------------------------------------------------------------------
__global__ void degree_kernel(const int* __restrict__ src, const int* __restrict__ dst,
                              int* __restrict__ outdeg, int* __restrict__ indeg) {
    int e = blockIdx.x * blockDim.x + threadIdx.x;
    if (e < NE) {
        atomicAdd(&outdeg[src[e]], 1);
        atomicAdd(&indeg[dst[e]], 1);
    }
}

__global__ void rsqrt_kernel(const int* __restrict__ deg, float* __restrict__ inv, int n) {
    int i = blockIdx.x * blockDim.x + threadIdx.x;
    if (i < n) {
        float d = (float)deg[i];
        inv[i] = rsqrtf(d < 1.0f ? 1.0f : d);
    }
}

// exclusive prefix scan of indeg[NN] -> row_ptr[NN+1]
__global__ __launch_bounds__(1024) void scan_kernel(const int* __restrict__ deg,
                                                    int* __restrict__ row_ptr) {
    __shared__ int wsum[16];
    __shared__ int chunk_base;
    if (threadIdx.x == 0) chunk_base = 0;
    __syncthreads();
    const int lane = threadIdx.x & 63;
    const int wid = threadIdx.x >> 6;
    for (int base = 0; base < NN; base += 1024) {
        int i = base + threadIdx.x;
        int v = (i < NN) ? deg[i] : 0;
        int s = v;
#pragma unroll
        for (int off = 1; off < 64; off <<= 1) {
            int t = __shfl_up(s, off, 64);
            if (lane >= off) s += t;
        }
        if (lane == 63) wsum[wid] = s;
        __syncthreads();
        if (wid == 0 && lane < 16) {
            int ws = wsum[lane];
#pragma unroll
            for (int off = 1; off < 16; off <<= 1) {
                int t = __shfl_up(ws, off, 64);
                if (lane >= off) ws += t;
            }
            wsum[lane] = ws;
        }
        __syncthreads();
        int cb = chunk_base;
        int woff = (wid > 0) ? wsum[wid - 1] : 0;
        if (i < NN) row_ptr[i] = cb + woff + s - v;
        int total = wsum[15];
        __syncthreads();
        if (threadIdx.x == 0) chunk_base = cb + total;
        __syncthreads();
    }
    if (threadIdx.x == 0) row_ptr[NN] = chunk_base;
}

__global__ void fill_kernel(const int* __restrict__ src, const int* __restrict__ dst,
                            const int* __restrict__ row_ptr, int* __restrict__ cursor,
                            int* __restrict__ col) {
    int e = blockIdx.x * blockDim.x + threadIdx.x;
    if (e < NE) {
        int d = dst[e];
        int pos = atomicAdd(&cursor[d], 1);
        col[row_ptr[d] + pos] = src[e];
    }
}

// ---------------------------------------------------------------------------
// feats fp32 -> bf16 (flat)
__global__ void featconv_kernel(const float* __restrict__ F, ushort_t* __restrict__ Fb) {
    int i = blockIdx.x * blockDim.x + threadIdx.x;   // over NN*256/8
    if (i >= NN * D_IN / 8) return;
    float4 a = *(const float4*)(F + (size_t)i * 8);
    float4 b = *(const float4*)(F + (size_t)i * 8 + 4);
    uint4 o;
    o.x = (uint_t)f2bf(a.x) | ((uint_t)f2bf(a.y) << 16);
    o.y = (uint_t)f2bf(a.z) | ((uint_t)f2bf(a.w) << 16);
    o.z = (uint_t)f2bf(b.x) | ((uint_t)f2bf(b.y) << 16);
    o.w = (uint_t)f2bf(b.z) | ((uint_t)f2bf(b.w) << 16);
    *(uint4*)(Fb + (size_t)i * 8) = o;
}

// ---------------------------------------------------------------------------
// Pack all weights into MFMA B-fragment order, bf16 (see R6 comment).
// ---------------------------------------------------------------------------
__global__ void packw_kernel(const float* __restrict__ W0,
                             const float* __restrict__ Wh,
                             const float* __restrict__ Wout,
                             ushort_t* __restrict__ W0p,
                             ushort_t* __restrict__ Whp,
                             ushort_t* __restrict__ Woutp) {
    int g = blockIdx.x * blockDim.x + threadIdx.x;
    int frag = g >> 6;
    int lane = g & 63;
    if (frag >= 368) return;
    const float* srcw;
    ushort_t* dstp;
    int fl, KF, M;
    if (frag < 64) {                     // W0
        fl = frag; KF = 8; M = 128;
        srcw = W0;
        dstp = W0p;
    } else if (frag < 64 + 192) {        // Wh
        int f2 = frag - 64;
        int l = f2 / 32; fl = f2 % 32; KF = 4; M = 128;
        srcw = Wh + (size_t)l * D_H * D_H;
        dstp = Whp + (size_t)l * 32 * 512;
    } else {                             // Wout blocks
        int f2 = frag - 256;
        int l = f2 / 16; fl = f2 % 16; KF = 4; M = 64;
        srcw = Wout + (size_t)l * D_H * D_OUT;
        dstp = Woutp + (size_t)l * 16 * 512;
    }
    int ct = fl / KF;
    int kt = fl % KF;
    int krow = kt * 32 + (lane >> 4) * 8;
    int cidx = ct * 16 + (lane & 15);
    ushort_t tmp[8];
#pragma unroll
    for (int j = 0; j < 8; j++)
        tmp[j] = f2bf(srcw[(size_t)(krow + j) * M + cidx]);
    uint4 o;
    o.x = (uint_t)tmp[0] | ((uint_t)tmp[1] << 16);
    o.y = (uint_t)tmp[2] | ((uint_t)tmp[3] << 16);
    o.z = (uint_t)tmp[4] | ((uint_t)tmp[5] << 16);
    o.w = (uint_t)tmp[6] | ((uint_t)tmp[7] << 16);
    *(uint4*)(dstp + (size_t)fl * 512 + lane * 8) = o;
}

// ---------------------------------------------------------------------------
// MFMA GEMM (bf16 in, no LDS) — unchanged from R6.
// ---------------------------------------------------------------------------
template <int KF, bool HAS_T, bool HAS_P>
__global__ __launch_bounds__(256) void gemm_mfma(
    const ushort_t* __restrict__ Xb,
    const ushort_t* __restrict__ W1p,
    const ushort_t* __restrict__ W2p,
    const float* __restrict__ scale,
    ushort_t* __restrict__ Tb,
    float* __restrict__ P,
    int nrows)
{
    constexpr int K = KF * 32;
    const int lane = threadIdx.x & 63;
    const int w = threadIdx.x >> 6;
    const int rg = w >> 1;
    const int cgrp = w & 1;
    const int row0 = blockIdx.x * 32 + rg * 16;

    int arow = row0 + (lane & 15);
    if (arow >= nrows) arow = nrows - 1;
    const ushort_t* xr = Xb + (size_t)arow * K + ((lane >> 4) * 8);
    sh8 a[KF];
#pragma unroll
    for (int kt = 0; kt < KF; kt++)
        a[kt] = *(const sh8*)(xr + kt * 32);

    const int crow0 = row0 + (lane >> 4) * 4;

    if (HAS_T) {
        float s[4];
#pragma unroll
        for (int r = 0; r < 4; r++) {
            int rw = crow0 + r;
            s[r] = scale[rw < nrows ? rw : nrows - 1];
        }
#pragma unroll
        for (int i = 0; i < 4; i++) {
            int ct = cgrp * 4 + i;
            f4 acc = {0.f, 0.f, 0.f, 0.f};
            const ushort_t* wp = W1p + ((size_t)(ct * KF) << 9) + lane * 8;
#pragma unroll
            for (int kt = 0; kt < KF; kt++)
                acc = __builtin_amdgcn_mfma_f32_16x16x32_bf16(
                    a[kt], *(const sh8*)(wp + ((size_t)kt << 9)), acc, 0, 0, 0);
            int colb = ct * 16 + (lane & 15);
#pragma unroll
            for (int r = 0; r < 4; r++) {
                int rw = crow0 + r;
                if (rw < nrows)
                    Tb[(size_t)rw * 128 + colb] = f2bf(acc[r] * s[r]);
            }
        }
    }
    if (HAS_P) {
#pragma unroll
        for (int i = 0; i < 2; i++) {
            int ct = cgrp * 2 + i;
            f4 acc = {0.f, 0.f, 0.f, 0.f};
            const ushort_t* wp = W2p + ((size_t)(ct * KF) << 9) + lane * 8;
#pragma unroll
            for (int kt = 0; kt < KF; kt++)
                acc = __builtin_amdgcn_mfma_f32_16x16x32_bf16(
                    a[kt], *(const sh8*)(wp + ((size_t)kt << 9)), acc, 0, 0, 0);
            int colb = ct * 16 + (lane & 15);
#pragma unroll
            for (int r = 0; r < 4; r++) {
                int rw = crow0 + r;
                if (rw < nrows) {
                    float* pp = P + (size_t)rw * 64 + colb;
                    *pp += acc[r];
                }
            }
        }
    }
}

// ---------------------------------------------------------------------------
// bf16 CSR gather, 4x-unrolled edge loop for MLP:
//   Yb[node,0:128] = bf16(relu( sum Tb[col[j],:] * scale + bias ))
// ---------------------------------------------------------------------------
__global__ __launch_bounds__(256) void gather_bf16_kernel(
    const ushort_t* __restrict__ Tb,
    const int* __restrict__ row_ptr,
    const int* __restrict__ col,
    const float* __restrict__ scale,
    const float* __restrict__ bias,
    ushort_t* __restrict__ Yb) {
    int idx = blockIdx.x * blockDim.x + threadIdx.x;
    int node = idx >> 4;
    int q = idx & 15;
    if (node >= NN) return;
    int beg = row_ptr[node];
    int end = row_ptr[node + 1];
    const uint_t* T32 = (const uint_t*)Tb;   // row = 64 uints
    float acc[8];
#pragma unroll
    for (int i = 0; i < 8; i++) acc[i] = 0.f;

    int j = beg;
    for (; j + 3 < end; j += 4) {
        int c0 = col[j], c1 = col[j + 1], c2 = col[j + 2], c3 = col[j + 3];
        uint4 u0 = *(const uint4*)(T32 + (size_t)c0 * 64 + q * 4);
        uint4 u1 = *(const uint4*)(T32 + (size_t)c1 * 64 + q * 4);
        uint4 u2 = *(const uint4*)(T32 + (size_t)c2 * 64 + q * 4);
        uint4 u3 = *(const uint4*)(T32 + (size_t)c3 * 64 + q * 4);
        uint_t w0[4] = {u0.x, u0.y, u0.z, u0.w};
        uint_t w1[4] = {u1.x, u1.y, u1.z, u1.w};
        uint_t w2[4] = {u2.x, u2.y, u2.z, u2.w};
        uint_t w3[4] = {u3.x, u3.y, u3.z, u3.w};
#pragma unroll
        for (int i = 0; i < 4; i++) {
            acc[2 * i] += (__uint_as_float(w0[i] << 16) + __uint_as_float(w1[i] << 16))
                        + (__uint_as_float(w2[i] << 16) + __uint_as_float(w3[i] << 16));
            acc[2 * i + 1] += (__uint_as_float(w0[i] & 0xFFFF0000u) + __uint_as_float(w1[i] & 0xFFFF0000u))
                            + (__uint_as_float(w2[i] & 0xFFFF0000u) + __uint_as_float(w3[i] & 0xFFFF0000u));
        }
    }
    for (; j < end; j++) {
        int c0 = col[j];
        uint4 u0 = *(const uint4*)(T32 + (size_t)c0 * 64 + q * 4);
        uint_t w0[4] = {u0.x, u0.y, u0.z, u0.w};
#pragma unroll
        for (int i = 0; i < 4; i++) {
            acc[2 * i]     += __uint_as_float(w0[i] << 16);
            acc[2 * i + 1] += __uint_as_float(w0[i] & 0xFFFF0000u);
        }
    }

    float s = scale[node];
    float h[8];
#pragma unroll
    for (int i = 0; i < 8; i++)
        h[i] = fmaxf(fmaf(acc[i], s, bias[q * 8 + i]), 0.f);
    uint4 o;
    o.x = (uint_t)f2bf(h[0]) | ((uint_t)f2bf(h[1]) << 16);
    o.y = (uint_t)f2bf(h[2]) | ((uint_t)f2bf(h[3]) << 16);
    o.z = (uint_t)f2bf(h[4]) | ((uint_t)f2bf(h[5]) << 16);
    o.w = (uint_t)f2bf(h[6]) | ((uint_t)f2bf(h[7]) << 16);
    *(uint4*)(Yb + (size_t)node * 128 + q * 8) = o;
}

// fp32 final gather, 4x-unrolled: out[node,0:64] = sum p[col[j],:] + bout
__global__ __launch_bounds__(256) void gather_f32_kernel(
    const float* __restrict__ P,
    const int* __restrict__ row_ptr,
    const int* __restrict__ col,
    const float* __restrict__ bias,
    float* __restrict__ Y) {
    int idx = blockIdx.x * blockDim.x + threadIdx.x;
    int node = idx >> 4;
    int q = idx & 15;
    if (node >= NN) return;
    int beg = row_ptr[node];
    int end = row_ptr[node + 1];
    float4 acc = make_float4(0.f, 0.f, 0.f, 0.f);
    int j = beg;
    for (; j + 3 < end; j += 4) {
        int c0 = col[j], c1 = col[j + 1], c2 = col[j + 2], c3 = col[j + 3];
        float4 v0 = *(const float4*)(P + (size_t)c0 * 64 + q * 4);
        float4 v1 = *(const float4*)(P + (size_t)c1 * 64 + q * 4);
        float4 v2 = *(const float4*)(P + (size_t)c2 * 64 + q * 4);
        float4 v3 = *(const float4*)(P + (size_t)c3 * 64 + q * 4);
        acc.x += (v0.x + v1.x) + (v2.x + v3.x);
        acc.y += (v0.y + v1.y) + (v2.y + v3.y);
        acc.z += (v0.z + v1.z) + (v2.z + v3.z);
        acc.w += (v0.w + v1.w) + (v2.w + v3.w);
    }
    for (; j < end; j++) {
        int c0 = col[j];
        float4 v0 = *(const float4*)(P + (size_t)c0 * 64 + q * 4);
        acc.x += v0.x; acc.y += v0.y; acc.z += v0.z; acc.w += v0.w;
    }
    float4 b = *(const float4*)(bias + q * 4);
    acc.x += b.x; acc.y += b.y; acc.z += b.z; acc.w += b.w;
    *(float4*)(Y + (size_t)node * 64 + q * 4) = acc;
}

// ---------------------------------------------------------------------------
extern "C" void kernel_launch(void* const* d_in, const int* in_sizes, int n_in,
                              void* d_out, int out_size, void* d_ws, size_t ws_size,
                              hipStream_t stream) {
    const float* feats = (const float*)d_in[0];
    const int*   src   = (const int*)d_in[1];
    const int*   dst   = (const int*)d_in[2];
    const float* W0    = (const float*)d_in[3];
    const float* b0    = (const float*)d_in[4];
    const float* Wh    = (const float*)d_in[5];
    const float* bh    = (const float*)d_in[6];
    const float* Wout  = (const float*)d_in[7];
    const float* bout  = (const float*)d_in[8];
    float* out = (float*)d_out;

    float* ws      = (float*)d_ws;
    float* inv_out = ws;                              // NN
    float* inv_in  = ws + NN;                         // NN
    float* p       = ws + 2 * NN;                     // NN*64 fp32
    ushort_t* tb   = (ushort_t*)(p + (size_t)NN * 64);      // NN*128 bf16
    ushort_t* ha   = tb + (size_t)NN * 128;           // NN*128 bf16
    ushort_t* hb   = ha + (size_t)NN * 128;           // NN*128 bf16
    ushort_t* fb   = hb + (size_t)NN * 128;           // NN*256 bf16
    ushort_t* w0p  = fb + (size_t)NN * 256;           // 64*512
    ushort_t* whp  = w0p + 64 * 512;                  // 192*512
    ushort_t* wop  = whp + 192 * 512;                 // 112*512
    int* ibase     = (int*)(wop + 112 * 512);
    int* outdeg_i  = ibase;                           // NN
    int* indeg_i   = ibase + NN;                      // NN
    int* row_ptr   = ibase + 2 * NN;                  // NN+1
    int* cursor    = ibase + 3 * NN + 1;              // NN
    int* col       = ibase + 4 * NN + 1;              // NE

    const int B = 256;
    const int gemm_blocks = (NN + 31) / 32;           // 938
    const int gather_blocks = (NN * 16 + B - 1) / B;

    // ---- CSR build + norms + conversions + packing ----
    hipMemsetAsync(outdeg_i, 0, 2 * NN * sizeof(int), stream);
    hipMemsetAsync(cursor, 0, NN * sizeof(int), stream);
    hipMemsetAsync(p, 0, (size_t)NN * D_OUT * sizeof(float), stream);
    degree_kernel<<<(NE + B - 1) / B, B, 0, stream>>>(src, dst, outdeg_i, indeg_i);
    rsqrt_kernel<<<(2 * NN + B - 1) / B, B, 0, stream>>>(outdeg_i, inv_out, 2 * NN);
    scan_kernel<<<1, 1024, 0, stream>>>(indeg_i, row_ptr);
    fill_kernel<<<(NE + B - 1) / B, B, 0, stream>>>(src, dst, row_ptr, cursor, col);
    featconv_kernel<<<(NN * D_IN / 8 + B - 1) / B, B, 0, stream>>>(feats, fb);
    packw_kernel<<<(368 * 64 + B - 1) / B, B, 0, stream>>>(W0, Wh, Wout, w0p, whp, wop);

    // ---- layer 0 ----
    gemm_mfma<8, true, false><<<gemm_blocks, 256, 0, stream>>>(
        fb, w0p, nullptr, inv_out, tb, nullptr, NN);
    gather_bf16_kernel<<<gather_blocks, B, 0, stream>>>(
        tb, row_ptr, col, inv_in, b0, ha);

    // ---- layers 1..6 fused with p += h_l @ Wout_l ----
    ushort_t* hcur = ha;
    ushort_t* hnext = hb;
    for (int l = 0; l < NL; l++) {
        gemm_mfma<4, true, true><<<gemm_blocks, 256, 0, stream>>>(
            hcur, whp + (size_t)l * 32 * 512, wop + (size_t)l * 16 * 512,
            inv_out, tb, p, NN);
        gather_bf16_kernel<<<gather_blocks, B, 0, stream>>>(
            tb, row_ptr, col, inv_in, bh + (size_t)l * D_H, hnext);
        ushort_t* tmp = hcur; hcur = hnext; hnext = tmp;
    }

    // ---- tail: p += h_6 @ Wout_6 ----
    gemm_mfma<4, false, true><<<gemm_blocks, 256, 0, stream>>>(
        hcur, nullptr, wop + (size_t)NL * 16 * 512, nullptr, nullptr, p, NN);

    // ---- out = gather(p) + bout ----
    gather_f32_kernel<<<gather_blocks, B, 0, stream>>>(p, row_ptr, col, bout, out);
}